// Round 15
// baseline (231.389 us; speedup 1.0000x reference)
//
#include <hip/hip_runtime.h>
#include <math.h>

#define NC     1000
#define DIM    2048
#define HALF   1024
#define NBATCH 8192
#define SBLK   512      // stream blocks
#define RPB    16       // rows per stream block
#define FBLK   2000     // finalize blocks (1000 classes x 2 col-halves)

typedef float f32x4 __attribute__((ext_vector_type(4)));

// ws layout (bytes):
// [0, 8192000)          sums  float[1000][2048]   (zeroed each call)
// [8192000, 8196000)    counts int[1000]          (zeroed each call)
// [8196096, 8198144)    partials float[512]       (fully rewritten)

// Phase 1: 512 blocks x 16 consecutive rows each -- perfectly balanced,
// perfectly coalesced. Scatter row into sums[y[i]] via HW f32 atomics
// (unsafeAtomicAdd -> global_atomic_add_f32, fire-and-forget, per-thread
// DISTINCT addresses so no same-address contention storm).
__global__ __launch_bounds__(256) void k_stream(
        const int*   __restrict__ y,
        const float* __restrict__ feat,
        const float* __restrict__ centers,
        float* __restrict__ sums,
        int*   __restrict__ counts,
        float* __restrict__ partials) {
    const int b = blockIdx.x;
    const int t = threadIdx.x;
    const int c0 = 4 * t;
    const int c1 = HALF + 4 * t;
    const int row0 = b * RPB;

    __shared__ int yl[RPB];
    if (t < RPB) yl[t] = y[row0 + t];
    __syncthreads();

    float lsum = 0.f;
    for (int k = 0; k < RPB; ++k) {
        const int i  = row0 + k;
        const int yi = yl[k];
        const float* fr = feat    + (size_t)i  * DIM;
        const float* cr = centers + (size_t)yi * DIM;
        f32x4 f0 = __builtin_nontemporal_load((const f32x4*)(fr + c0));
        f32x4 f1 = __builtin_nontemporal_load((const f32x4*)(fr + c1));
        f32x4 e0 = *(const f32x4*)(cr + c0);   // cached: 8.4 MB table, hot
        f32x4 e1 = *(const f32x4*)(cr + c1);
        f32x4 d0 = f0 - e0, d1 = f1 - e1;
        f32x4 sq = d0 * d0 + d1 * d1;
        lsum += sq.x + sq.y + sq.z + sq.w;

        float* sr = sums + (size_t)yi * DIM;
        unsafeAtomicAdd(sr + c0 + 0, f0.x);
        unsafeAtomicAdd(sr + c0 + 1, f0.y);
        unsafeAtomicAdd(sr + c0 + 2, f0.z);
        unsafeAtomicAdd(sr + c0 + 3, f0.w);
        unsafeAtomicAdd(sr + c1 + 0, f1.x);
        unsafeAtomicAdd(sr + c1 + 1, f1.y);
        unsafeAtomicAdd(sr + c1 + 2, f1.z);
        unsafeAtomicAdd(sr + c1 + 3, f1.w);
        if (t == 0) atomicAdd(&counts[yi], 1);
    }

    // block-reduce lsum -> partials[b]
    for (int sh = 32; sh > 0; sh >>= 1) lsum += __shfl_down(lsum, sh);
    __shared__ float red[4];
    if ((t & 63) == 0) red[t >> 6] = lsum;
    __syncthreads();
    if (t == 0) partials[b] = red[0] + red[1] + red[2] + red[3];
}

// Phase 2: grad = coeff * (centers - sums/n); block 0 also reduces the 512
// loss partials (safe: same-stream kernel order) -- no extra dispatch.
__global__ __launch_bounds__(256) void k_fin(
        const float* __restrict__ sums,
        const int*   __restrict__ counts,
        const float* __restrict__ centers,
        const float* __restrict__ partials,
        float* __restrict__ grad_out,    // d_out + 1 (4B-aligned only)
        float* __restrict__ out) {
    const int bb = blockIdx.x;
    const int c = bb >> 1;
    const int h = bb & 1;
    const int t = threadIdx.x;
    const int col = h * HALF + 4 * t;

    const int n = counts[c];
    f32x4 s   = *(const f32x4*)(sums    + (size_t)c * DIM + col);
    f32x4 cen = *(const f32x4*)(centers + (size_t)c * DIM + col);

    f32x4 g = (f32x4)(0.f);
    if (n > 0) {
        float fn = (float)n;
        float coeff = fn / (1.0f + fn);
        g = coeff * (cen - s * (1.0f / fn));
    }
    float* go = grad_out + (size_t)c * DIM + col;   // odd base -> scalar stores
    go[0] = g.x; go[1] = g.y; go[2] = g.z; go[3] = g.w;

    if (bb == 0) {
        float v = partials[t] + partials[t + 256];
        for (int sh = 32; sh > 0; sh >>= 1) v += __shfl_down(v, sh);
        __shared__ float red[4];
        if ((t & 63) == 0) red[t >> 6] = v;
        __syncthreads();
        if (t == 0) {
            float tot = red[0] + red[1] + red[2] + red[3];
            out[0] = 0.5f * sqrtf(tot) / (float)NBATCH;
        }
    }
}

extern "C" void kernel_launch(void* const* d_in, const int* in_sizes, int n_in,
                              void* d_out, int out_size, void* d_ws, size_t ws_size,
                              hipStream_t stream) {
    const int*   y       = (const int*)d_in[0];
    const float* feat    = (const float*)d_in[1];
    const float* centers = (const float*)d_in[2];
    float* out = (float*)d_out;

    char* ws = (char*)d_ws;
    float* sums     = (float*)ws;
    int*   counts   = (int*)(ws + 8192000);
    float* partials = (float*)(ws + 8196096);

    hipMemsetAsync(d_ws, 0, 8196000, stream);   // sums + counts
    k_stream<<<SBLK, 256, 0, stream>>>(y, feat, centers, sums, counts, partials);
    k_fin  <<<FBLK, 256, 0, stream>>>(sums, counts, centers, partials, out + 1, out);
}

// Round 16
// 25.230 us; speedup vs baseline: 9.1714x; 9.1714x over previous
//
#include <hip/hip_runtime.h>
#include <math.h>

#define NC     1000
#define NBLK   2000     // 2 column-half blocks per class
#define DIM    2048
#define HALF   1024
#define NBATCH 8192

typedef float f32x4 __attribute__((ext_vector_type(4)));
typedef int   i32x4 __attribute__((ext_vector_type(4)));

// FINAL (= R11, best measured: 24.2 us). Gather structure:
// Grid: 2000 blocks = 1000 classes x 2 column halves; 256 threads.
// Thread t of block (c,h) owns cols h*1024 + [4t, 4t+4).
// Each block scans y (L2-resident, 32 KB) for its class's rows, gathers the
// feat rows once, producing the per-class sum -> grad half + loss partial.
// Separate tiny k_loss reduce (all in-kernel finalize variants measured
// 10-70 us WORSE: same-line device-scope RMW serializes on the 8-XCD fabric).
__global__ __launch_bounds__(256) void k_main(
        const int*   __restrict__ y,
        const float* __restrict__ feat,
        const float* __restrict__ centers,
        float* __restrict__ grad_out,     // d_out + 1 (4B-aligned only)
        float* __restrict__ partials) {   // [2000]
    const int c = blockIdx.x >> 1;
    const int h = blockIdx.x & 1;
    const int t = threadIdx.x;
    const int col = h * HALF + t * 4;

    const f32x4 cen = *(const f32x4*)(centers + (size_t)c * DIM + col);

    __shared__ unsigned short sidx[NBATCH];   // 16 KB worst case
    __shared__ int scur;
    if (t == 0) scur = 0;
    __syncthreads();

    // vectorized scan of y: 8192 ints as 2048 int4, 8 per thread
    const i32x4* y4 = (const i32x4*)y;
    for (int j = t; j < NBATCH / 4; j += 256) {
        i32x4 v = y4[j];
        int base = 4 * j;
        if (v.x == c) sidx[atomicAdd(&scur, 1)] = (unsigned short)(base + 0);
        if (v.y == c) sidx[atomicAdd(&scur, 1)] = (unsigned short)(base + 1);
        if (v.z == c) sidx[atomicAdd(&scur, 1)] = (unsigned short)(base + 2);
        if (v.w == c) sidx[atomicAdd(&scur, 1)] = (unsigned short)(base + 3);
    }
    __syncthreads();
    const int n = scur;

    f32x4 acc = (f32x4)(0.f);
    float lsum = 0.f;

    int r = 0;
    for (; r + 4 <= n; r += 4) {
        int i0 = sidx[r], i1 = sidx[r+1], i2 = sidx[r+2], i3 = sidx[r+3];
        f32x4 v0 = *(const f32x4*)(feat + (size_t)i0 * DIM + col);
        f32x4 v1 = *(const f32x4*)(feat + (size_t)i1 * DIM + col);
        f32x4 v2 = *(const f32x4*)(feat + (size_t)i2 * DIM + col);
        f32x4 v3 = *(const f32x4*)(feat + (size_t)i3 * DIM + col);
        acc += v0 + v1 + v2 + v3;
        f32x4 d0 = v0 - cen, d1 = v1 - cen, d2 = v2 - cen, d3 = v3 - cen;
        f32x4 sq = d0 * d0 + d1 * d1 + d2 * d2 + d3 * d3;
        lsum += sq.x + sq.y + sq.z + sq.w;
    }
    for (; r < n; ++r) {
        int i0 = sidx[r];
        f32x4 v0 = *(const f32x4*)(feat + (size_t)i0 * DIM + col);
        acc += v0;
        f32x4 d0 = v0 - cen;
        f32x4 sq = d0 * d0;
        lsum += sq.x + sq.y + sq.z + sq.w;
    }

    // grad = coeff * (centers - mean); coeff = n/(1+n); zero when n == 0
    f32x4 g = (f32x4)(0.f);
    if (n > 0) {
        float fn = (float)n;
        float inv = 1.0f / fn;
        float coeff = fn / (1.0f + fn);
        g = coeff * (cen - acc * inv);
    }
    float* go = grad_out + (size_t)c * DIM + col;   // odd base -> scalar stores
    go[0] = g.x; go[1] = g.y; go[2] = g.z; go[3] = g.w;

    // block-reduce lsum (4 waves)
    for (int sh = 32; sh > 0; sh >>= 1) lsum += __shfl_down(lsum, sh);
    __shared__ float red[4];
    if ((t & 63) == 0) red[t >> 6] = lsum;
    __syncthreads();
    if (t == 0) partials[blockIdx.x] = red[0] + red[1] + red[2] + red[3];
}

__global__ void k_loss(const float* __restrict__ partials, float* __restrict__ out) {
    __shared__ float s[256];
    int t = threadIdx.x;
    float v = 0.f;
    for (int i = t; i < NBLK; i += 256) v += partials[i];
    s[t] = v;
    __syncthreads();
    for (int off = 128; off > 0; off >>= 1) {
        if (t < off) s[t] += s[t + off];
        __syncthreads();
    }
    if (t == 0) out[0] = 0.5f * sqrtf(s[0]) / (float)NBATCH;
}

extern "C" void kernel_launch(void* const* d_in, const int* in_sizes, int n_in,
                              void* d_out, int out_size, void* d_ws, size_t ws_size,
                              hipStream_t stream) {
    const int*   y       = (const int*)d_in[0];
    const float* feat    = (const float*)d_in[1];
    const float* centers = (const float*)d_in[2];
    float* out = (float*)d_out;
    float* partials = (float*)d_ws;   // 2000 floats, fully rewritten each call

    k_main<<<NBLK, 256, 0, stream>>>(y, feat, centers, out + 1, partials);
    k_loss<<<1, 256, 0, stream>>>(partials, out);
}